// Round 12
// baseline (313.081 us; speedup 1.0000x reference)
//
#include <hip/hip_runtime.h>
#include <math.h>

#define NN 1024   // nodes
#define DD 128    // dim
#define BB 1024   // graphs
#define TI 8      // i-rows per pairwise block
#define TJ 32     // j-rows per pairwise block

typedef float floatx4 __attribute__((ext_vector_type(4)));

__device__ __forceinline__ float waveReduceSum(float v) {
#pragma unroll
  for (int off = 32; off > 0; off >>= 1) v += __shfl_xor(v, off);
  return v;
}
__device__ __forceinline__ float waveReduceMax(float v) {
#pragma unroll
  for (int off = 32; off > 0; off >>= 1) v = fmaxf(v, __shfl_xor(v, off));
  return v;
}

// K1 prep, 256 threads = 4 independent waves; wave u handles unit
// b*4+u: units 0..NN-1 normalize node rows, NN..NN+BB-1 normalize graph
// rows, NN+BB..NN+2BB-1 gm row max/denominator. All reductions wave-local.
__global__ __launch_bounds__(256) void prep_kernel(
    const float* __restrict__ ne, const float* __restrict__ ge,
    const float* __restrict__ gm, float* __restrict__ ne_n,
    float* __restrict__ ge_n, float* __restrict__ gm_max,
    float* __restrict__ gm_den) {
  int unit = blockIdx.x * 4 + (threadIdx.x >> 6);
  int lane = threadIdx.x & 63;
  if (unit < NN + BB) {
    const float* src;
    float* dst;
    if (unit < NN) { src = ne + (size_t)unit * DD; dst = ne_n + (size_t)unit * DD; }
    else { src = ge + (size_t)(unit - NN) * DD; dst = ge_n + (size_t)(unit - NN) * DD; }
    float2 v = ((const float2*)src)[lane];
    float ss = v.x * v.x + v.y * v.y;
    ss = waveReduceSum(ss);
    float scale = 1.0f / fmaxf(sqrtf(ss), 1e-12f);
    float2 o;
    o.x = v.x * scale;
    o.y = v.y * scale;
    ((float2*)dst)[lane] = o;
  } else {
    int row = unit - (NN + BB);
    const float4* r = (const float4*)(gm + (size_t)row * BB);
    float vals[16];
    float m = -INFINITY;
#pragma unroll
    for (int k = 0; k < 4; ++k) {
      float4 v = r[lane + 64 * k];
      vals[k * 4 + 0] = v.x; vals[k * 4 + 1] = v.y;
      vals[k * 4 + 2] = v.z; vals[k * 4 + 3] = v.w;
      m = fmaxf(m, fmaxf(fmaxf(v.x, v.y), fmaxf(v.z, v.w)));
    }
    m = waveReduceMax(m);
    float s = 0.f;
#pragma unroll
    for (int t = 0; t < 16; ++t) s += expf(vals[t] - m);
    s = waveReduceSum(s);
    if (lane == 0) { gm_max[row] = m; gm_den[row] = s; }
  }
}

// K2 fused: heterogeneous INTERLEAVED grid (6144 blocks), mod-3 (R10's
// best layout: ~1/3 loss density across the whole timeline).
//   b % 3 == 2 -> loss block   lossId = b/3   (0..2047)
//   else       -> pairwise blk pwId = (b/3)*2 + (b%3)  (0..4095)
// NEW vs R10: pairwise stores are NONTEMPORAL (bypass L2). Gathers now
// come from LDS, so NT is pure upside: keeps L2 for the loss blocks'
// working set (nen/gen/gm) instead of 1 GB of write-allocate churn.
// Shared memory union: pairwise 20672 B, loss 4640 B.
__global__ __launch_bounds__(256) void fused_kernel(
    const float* __restrict__ nen, const float* __restrict__ gen,
    const float* __restrict__ gm, const float* __restrict__ gm_max,
    const float* __restrict__ gm_den, float* __restrict__ out_logits,
    float* __restrict__ outp, float* __restrict__ node_partial,
    float* __restrict__ graph_partial) {
  __shared__ __align__(16) char smem[20672];
  int b = blockIdx.x;
  int tid = threadIdx.x;
  int lane = tid & 63;
  int w = tid >> 6;
  int m3 = b % 3;

  if (m3 != 2) {
    // ---------------- pairwise block ----------------
    int pwId = (b / 3) * 2 + m3;
    int bi = pwId >> 5, bj = pwId & 31;
    int I0 = bi * TI, J0 = bj * TJ;
    float (*SHI)[DD] = (float (*)[DD])smem;                    // 4096 B
    float (*SHJ)[DD] = (float (*)[DD])(smem + 4096);           // 16384 B
    float* LJ0 = (float*)(smem + 20480);                       // 128 B
    float* LI0 = (float*)(smem + 20608);                       // 32 B
    float* LI0N = (float*)(smem + 20640);                      // 32 B

#pragma unroll
    for (int p = 0; p < 5; ++p) {
      int task = tid + 256 * p;   // 0..1279 = 40 rows x 32 float4
      int row = task >> 5;
      int c4 = task & 31;
      const float* src = (row < TI) ? nen + (size_t)(I0 + row) * DD
                                    : nen + (size_t)(J0 + row - TI) * DD;
      floatx4 A = *(const floatx4*)(src + 4 * c4);
      float nxt = __shfl_down(A.x, 1);  // c4==31 lanes: pad (unused)
      floatx4 Sv;
      Sv.x = A.y; Sv.y = A.z; Sv.z = A.w; Sv.w = nxt;
      float* dst = (row < TI) ? &SHI[row][4 * c4] : &SHJ[row - TI][4 * c4];
      *(floatx4*)dst = Sv;
      if (c4 == 0) {
        if (row < TI) {
          LI0[row] = A.x;
          int nr = I0 + row + 1;
          if (nr > 1023) nr = 0;      // value unused (global tail)
          LI0N[row] = nen[(size_t)nr * DD];
        } else {
          LJ0[row - TI] = A.x;
        }
      }
    }
    __syncthreads();

    bool is31 = (lane == 31);
    bool is63 = (lane == 63);
    bool patch = is31 | is63;
    bool lastSeg = (bj == 31) && (w == 3);  // with q==7 -> jc==31
    bool tailThread = (pwId == 4095) && (tid == 255);

    for (int ic = 0; ic < TI; ++ic) {
      float li0 = LI0[ic];
      float li0n = LI0N[ic];
      size_t segf = (((size_t)(I0 + ic) << 10) + (size_t)J0) << 8;
      float* gb = outp + segf + 1 + 4 * tid;
#pragma unroll
      for (int q = 0; q < 8; ++q) {
        int jc = w + 4 * q;  // wave-uniform
        const float* addr = (lane < 32) ? &SHI[ic][4 * lane]
                                        : &SHJ[jc][4 * (lane - 32)];
        floatx4 v = *(const floatx4*)addr;
        float lj0 = LJ0[jc];  // broadcast
        float spec = is31 ? lj0 : ((lastSeg && q == 7) ? li0n : li0);
        v.w = patch ? spec : v.w;
        if (tailThread && ic == TI - 1 && q == 7) {
          gb[0] = v.x; gb[1] = v.y; gb[2] = v.z;  // e = 2^28-3..2^28-1
        } else {
          __builtin_nontemporal_store(v, (floatx4*)gb);
        }
        gb += 1024;
      }
    }
    if (pwId == 0 && tid == 0) outp[0] = nen[0];  // head element e=0
    return;
  }

  // ---------------- loss block ----------------
  int lossId = b / 3;
  float* q = (float*)smem;            // 128 floats
  float* logits = q + DD;             // 1024 floats
  float* red = logits + NN;           // 8 floats
  int g = lane >> 4, gl = lane & 15;

  if (lossId < 1024) {
    int i = lossId;
    if (tid < DD) q[tid] = nen[(size_t)i * DD + tid];
    __syncthreads();
    const float4* qv = (const float4*)q;
    float4 b0 = qv[gl * 2], b1 = qv[gl * 2 + 1];
#pragma unroll 4
    for (int p = 0; p < 64; ++p) {
      int j = p * 16 + w * 4 + g;
      const float4* rowp = (const float4*)(nen + (size_t)j * DD);
      float4 a0 = rowp[gl * 2], a1 = rowp[gl * 2 + 1];
      float acc = a0.x * b0.x + a0.y * b0.y + a0.z * b0.z + a0.w * b0.w +
                  a1.x * b1.x + a1.y * b1.y + a1.z * b1.z + a1.w * b1.w;
      acc += __shfl_xor(acc, 1);
      acc += __shfl_xor(acc, 2);
      acc += __shfl_xor(acc, 4);
      acc += __shfl_xor(acc, 8);
      if (gl == 0) logits[j] = acc;
    }
    __syncthreads();
    float lv[4];
    float m = -INFINITY;
#pragma unroll
    for (int k = 0; k < 4; ++k) {
      lv[k] = logits[tid + 256 * k];
      m = fmaxf(m, lv[k]);
    }
    m = waveReduceMax(m);
    if (lane == 0) red[w] = m;
    __syncthreads();
    float M = fmaxf(fmaxf(red[0], red[1]), fmaxf(red[2], red[3]));
    float s = 0.f;
#pragma unroll
    for (int k = 0; k < 4; ++k) s += expf(lv[k] - M);
    s = waveReduceSum(s);
    if (lane == 0) red[4 + w] = s;
    __syncthreads();
    float S = red[4] + red[5] + red[6] + red[7];
    if (tid == 0) node_partial[i] = logits[i] - (M + logf(S));
  } else {
    // graph loss row i. logits matrix symmetric (bitwise: same reduction
    // order) so lpT == lp; fold both loss terms into one weighted sum.
    int i = lossId - 1024;
    if (tid < DD) q[tid] = gen[(size_t)i * DD + tid];
    __syncthreads();
    const float4* qv = (const float4*)q;
    float4 b0 = qv[gl * 2], b1 = qv[gl * 2 + 1];
#pragma unroll 4
    for (int p = 0; p < 64; ++p) {
      int j = p * 16 + w * 4 + g;
      const float4* rowp = (const float4*)(gen + (size_t)j * DD);
      float4 a0 = rowp[gl * 2], a1 = rowp[gl * 2 + 1];
      float acc = a0.x * b0.x + a0.y * b0.y + a0.z * b0.z + a0.w * b0.w +
                  a1.x * b1.x + a1.y * b1.y + a1.z * b1.z + a1.w * b1.w;
      acc += __shfl_xor(acc, 1);
      acc += __shfl_xor(acc, 2);
      acc += __shfl_xor(acc, 4);
      acc += __shfl_xor(acc, 8);
      if (gl == 0) logits[j] = acc;
    }
    __syncthreads();
    float lv[4];
    float m = -INFINITY;
#pragma unroll
    for (int k = 0; k < 4; ++k) {
      lv[k] = logits[tid + 256 * k];
      m = fmaxf(m, lv[k]);
      out_logits[(size_t)i * BB + tid + 256 * k] = lv[k];
    }
    m = waveReduceMax(m);
    if (lane == 0) red[w] = m;
    __syncthreads();
    float M = fmaxf(fmaxf(red[0], red[1]), fmaxf(red[2], red[3]));
    float s = 0.f;
#pragma unroll
    for (int k = 0; k < 4; ++k) s += expf(lv[k] - M);
    s = waveReduceSum(s);
    if (lane == 0) red[4 + w] = s;
    __syncthreads();
    float S = red[4] + red[5] + red[6] + red[7];
    float lse = M + logf(S);
    float gmx_i = gm_max[i];
    float inv_i = 1.0f / gm_den[i];
    float c = 0.f;
#pragma unroll
    for (int k = 0; k < 4; ++k) {
      int j = tid + 256 * k;
      float lp = lv[k] - lse;
      float wij = expf(gm[(size_t)i * BB + j] - gmx_i) * inv_i;
      float wji = expf(gm[(size_t)j * BB + i] - gm_max[j]) / gm_den[j];
      c += (wij + wji) * lp;
    }
    c = waveReduceSum(c);
    __syncthreads();
    if (lane == 0) red[w] = c;
    __syncthreads();
    if (tid == 0) graph_partial[i] = red[0] + red[1] + red[2] + red[3];
  }
}

// K3: deterministic final reduce of the 1024-element partial arrays.
__global__ __launch_bounds__(256) void final_kernel(
    const float* __restrict__ node_partial,
    const float* __restrict__ graph_partial, float* __restrict__ out) {
  int tid = threadIdx.x;
  int lane = tid & 63, wid = tid >> 6;
  __shared__ float red[8];
  float ns = 0.f, gs = 0.f;
#pragma unroll
  for (int k = 0; k < 4; ++k) {
    ns += node_partial[tid + 256 * k];
    gs += graph_partial[tid + 256 * k];
  }
  ns = waveReduceSum(ns);
  gs = waveReduceSum(gs);
  if (lane == 0) { red[wid] = ns; red[4 + wid] = gs; }
  __syncthreads();
  if (tid == 0) {
    float nsum = red[0] + red[1] + red[2] + red[3];
    float gsum = red[4] + red[5] + red[6] + red[7];
    float node_loss = -nsum / (float)NN;
    float graph_loss = -gsum / (float)BB;
    float loss = 0.5f * node_loss + 0.5f * graph_loss;
    out[0] = loss;
    out[1] = node_loss;
    out[2] = graph_loss;
  }
}

extern "C" void kernel_launch(void* const* d_in, const int* in_sizes, int n_in,
                              void* d_out, int out_size, void* d_ws,
                              size_t ws_size, hipStream_t stream) {
  const float* ne = (const float*)d_in[0];   // [1024,128]
  const float* ge = (const float*)d_in[1];   // [1024,128]
  const float* gm = (const float*)d_in[2];   // [1024,1024]
  float* out = (float*)d_out;
  float* ws = (float*)d_ws;

  float* ne_n = ws;                    // 131072
  float* ge_n = ws + 131072;           // 131072
  float* gm_max = ws + 262144;         // 1024
  float* gm_den = ws + 263168;         // 1024
  float* node_partial = ws + 264192;   // 1024
  float* graph_partial = ws + 265216;  // 1024

  float* out_logits = out + 3;                       // [1024,1024]
  float* out_pair = out + 3 + (size_t)NN * NN;       // [1024*1024, 256]

  hipLaunchKernelGGL(prep_kernel, dim3((NN + 2 * BB) / 4), dim3(256), 0,
                     stream, ne, ge, gm, ne_n, ge_n, gm_max, gm_den);
  hipLaunchKernelGGL(fused_kernel, dim3(6144), dim3(256), 0, stream,
                     ne_n, ge_n, gm, gm_max, gm_den, out_logits,
                     out_pair, node_partial, graph_partial);
  hipLaunchKernelGGL(final_kernel, dim3(1), dim3(256), 0, stream,
                     node_partial, graph_partial, out);
}

// Round 13
// 239.787 us; speedup vs baseline: 1.3057x; 1.3057x over previous
//
#include <hip/hip_runtime.h>
#include <math.h>

#define NN 1024   // nodes
#define DD 128    // dim
#define BB 1024   // graphs
#define TI 4      // i-rows per pairwise block
#define TJ 32     // j-rows per pairwise block

typedef float floatx4 __attribute__((ext_vector_type(4)));

__device__ __forceinline__ float waveReduceSum(float v) {
#pragma unroll
  for (int off = 32; off > 0; off >>= 1) v += __shfl_xor(v, off);
  return v;
}
__device__ __forceinline__ float waveReduceMax(float v) {
#pragma unroll
  for (int off = 32; off > 0; off >>= 1) v = fmaxf(v, __shfl_xor(v, off));
  return v;
}

// K1 prep, 256 threads = 4 independent waves; wave u handles unit
// b*4+u: units 0..NN-1 normalize node rows, NN..NN+BB-1 normalize graph
// rows, NN+BB..NN+2BB-1 gm row max/denominator. All reductions wave-local.
__global__ __launch_bounds__(256) void prep_kernel(
    const float* __restrict__ ne, const float* __restrict__ ge,
    const float* __restrict__ gm, float* __restrict__ ne_n,
    float* __restrict__ ge_n, float* __restrict__ gm_max,
    float* __restrict__ gm_den) {
  int unit = blockIdx.x * 4 + (threadIdx.x >> 6);
  int lane = threadIdx.x & 63;
  if (unit < NN + BB) {
    const float* src;
    float* dst;
    if (unit < NN) { src = ne + (size_t)unit * DD; dst = ne_n + (size_t)unit * DD; }
    else { src = ge + (size_t)(unit - NN) * DD; dst = ge_n + (size_t)(unit - NN) * DD; }
    float2 v = ((const float2*)src)[lane];
    float ss = v.x * v.x + v.y * v.y;
    ss = waveReduceSum(ss);
    float scale = 1.0f / fmaxf(sqrtf(ss), 1e-12f);
    float2 o;
    o.x = v.x * scale;
    o.y = v.y * scale;
    ((float2*)dst)[lane] = o;
  } else {
    int row = unit - (NN + BB);
    const float4* r = (const float4*)(gm + (size_t)row * BB);
    float vals[16];
    float m = -INFINITY;
#pragma unroll
    for (int k = 0; k < 4; ++k) {
      float4 v = r[lane + 64 * k];
      vals[k * 4 + 0] = v.x; vals[k * 4 + 1] = v.y;
      vals[k * 4 + 2] = v.z; vals[k * 4 + 3] = v.w;
      m = fmaxf(m, fmaxf(fmaxf(v.x, v.y), fmaxf(v.z, v.w)));
    }
    m = waveReduceMax(m);
    float s = 0.f;
#pragma unroll
    for (int t = 0; t < 16; ++t) s += expf(vals[t] - m);
    s = waveReduceSum(s);
    if (lane == 0) { gm_max[row] = m; gm_den[row] = s; }
  }
}

// K2 fused: heterogeneous INTERLEAVED grid (10240 blocks), loss 1-in-5.
//   b % 5 == 4 -> loss block  lossId = b/5          (0..2047)
//   else       -> pairwise    pwId = (b/5)*4 + b%5  (0..8191)
// vs R10: pairwise tile halved (TI=4) -> 8192 blocks, block lifetime
// ~50us instead of ~95us -> 4 scheduling generations instead of 2.28,
// shrinking the ragged-tail idle at kernel end. Stores CACHED (NT ruled
// out: R2/R4/R12 all regressed). LDS 19136 B -> 8 blocks/CU.
__global__ __launch_bounds__(256) void fused_kernel(
    const float* __restrict__ nen, const float* __restrict__ gen,
    const float* __restrict__ gm, const float* __restrict__ gm_max,
    const float* __restrict__ gm_den, float* __restrict__ out_logits,
    float* __restrict__ outp, float* __restrict__ node_partial,
    float* __restrict__ graph_partial) {
  __shared__ __align__(16) char smem[19136];
  int b = blockIdx.x;
  int tid = threadIdx.x;
  int lane = tid & 63;
  int w = tid >> 6;
  int m5 = b % 5;

  if (m5 != 4) {
    // ---------------- pairwise block ----------------
    int pwId = (b / 5) * 4 + m5;
    int bi = pwId >> 5, bj = pwId & 31;
    int I0 = bi * TI, J0 = bj * TJ;
    float (*SHI)[DD] = (float (*)[DD])smem;                    // 2048 B
    float (*SHJ)[DD] = (float (*)[DD])(smem + 2048);           // 16384 B
    float* LJ0 = (float*)(smem + 18432);                       // 128 B
    float* LI0 = (float*)(smem + 18560);                       // 16 B
    float* LI0N = (float*)(smem + 18576);                      // 16 B

    // stage 36 rows x 32 float4 = 1152 tasks, 5 sweeps with bounds check.
#pragma unroll
    for (int p = 0; p < 5; ++p) {
      int task = tid + 256 * p;   // 0..1279; valid < 1152
      if (task < (TI + TJ) * 32) {
        int row = task >> 5;
        int c4 = task & 31;
        const float* src = (row < TI) ? nen + (size_t)(I0 + row) * DD
                                      : nen + (size_t)(J0 + row - TI) * DD;
        floatx4 A = *(const floatx4*)(src + 4 * c4);
        float nxt = __shfl_down(A.x, 1);  // c4==31 lanes: pad (unused)
        floatx4 Sv;
        Sv.x = A.y; Sv.y = A.z; Sv.z = A.w; Sv.w = nxt;
        float* dst = (row < TI) ? &SHI[row][4 * c4] : &SHJ[row - TI][4 * c4];
        *(floatx4*)dst = Sv;
        if (c4 == 0) {
          if (row < TI) {
            LI0[row] = A.x;
            int nr = I0 + row + 1;
            if (nr > 1023) nr = 0;      // value unused (global tail)
            LI0N[row] = nen[(size_t)nr * DD];
          } else {
            LJ0[row - TI] = A.x;
          }
        }
      }
    }
    __syncthreads();

    bool is31 = (lane == 31);
    bool is63 = (lane == 63);
    bool patch = is31 | is63;
    bool lastSeg = (bj == 31) && (w == 3);  // with q==7 -> jc==31
    bool tailThread = (pwId == 8191) && (tid == 255);

    for (int ic = 0; ic < TI; ++ic) {
      float li0 = LI0[ic];
      float li0n = LI0N[ic];
      size_t segf = (((size_t)(I0 + ic) << 10) + (size_t)J0) << 8;
      float* gb = outp + segf + 1 + 4 * tid;
#pragma unroll
      for (int q = 0; q < 8; ++q) {
        int jc = w + 4 * q;  // wave-uniform
        const float* addr = (lane < 32) ? &SHI[ic][4 * lane]
                                        : &SHJ[jc][4 * (lane - 32)];
        floatx4 v = *(const floatx4*)addr;
        float lj0 = LJ0[jc];  // broadcast
        float spec = is31 ? lj0 : ((lastSeg && q == 7) ? li0n : li0);
        v.w = patch ? spec : v.w;
        if (tailThread && ic == TI - 1 && q == 7) {
          gb[0] = v.x; gb[1] = v.y; gb[2] = v.z;  // e = 2^28-3..2^28-1
        } else {
          *(floatx4*)gb = v;  // cached aligned 16B store
        }
        gb += 1024;
      }
    }
    if (pwId == 0 && tid == 0) outp[0] = nen[0];  // head element e=0
    return;
  }

  // ---------------- loss block ----------------
  int lossId = b / 5;
  float* q = (float*)smem;            // 128 floats
  float* logits = q + DD;             // 1024 floats
  float* red = logits + NN;           // 8 floats
  int g = lane >> 4, gl = lane & 15;

  if (lossId < 1024) {
    int i = lossId;
    if (tid < DD) q[tid] = nen[(size_t)i * DD + tid];
    __syncthreads();
    const float4* qv = (const float4*)q;
    float4 b0 = qv[gl * 2], b1 = qv[gl * 2 + 1];
#pragma unroll 4
    for (int p = 0; p < 64; ++p) {
      int j = p * 16 + w * 4 + g;
      const float4* rowp = (const float4*)(nen + (size_t)j * DD);
      float4 a0 = rowp[gl * 2], a1 = rowp[gl * 2 + 1];
      float acc = a0.x * b0.x + a0.y * b0.y + a0.z * b0.z + a0.w * b0.w +
                  a1.x * b1.x + a1.y * b1.y + a1.z * b1.z + a1.w * b1.w;
      acc += __shfl_xor(acc, 1);
      acc += __shfl_xor(acc, 2);
      acc += __shfl_xor(acc, 4);
      acc += __shfl_xor(acc, 8);
      if (gl == 0) logits[j] = acc;
    }
    __syncthreads();
    float lv[4];
    float m = -INFINITY;
#pragma unroll
    for (int k = 0; k < 4; ++k) {
      lv[k] = logits[tid + 256 * k];
      m = fmaxf(m, lv[k]);
    }
    m = waveReduceMax(m);
    if (lane == 0) red[w] = m;
    __syncthreads();
    float M = fmaxf(fmaxf(red[0], red[1]), fmaxf(red[2], red[3]));
    float s = 0.f;
#pragma unroll
    for (int k = 0; k < 4; ++k) s += expf(lv[k] - M);
    s = waveReduceSum(s);
    if (lane == 0) red[4 + w] = s;
    __syncthreads();
    float S = red[4] + red[5] + red[6] + red[7];
    if (tid == 0) node_partial[i] = logits[i] - (M + logf(S));
  } else {
    // graph loss row i. logits matrix symmetric (bitwise: same reduction
    // order) so lpT == lp; fold both loss terms into one weighted sum.
    int i = lossId - 1024;
    if (tid < DD) q[tid] = gen[(size_t)i * DD + tid];
    __syncthreads();
    const float4* qv = (const float4*)q;
    float4 b0 = qv[gl * 2], b1 = qv[gl * 2 + 1];
#pragma unroll 4
    for (int p = 0; p < 64; ++p) {
      int j = p * 16 + w * 4 + g;
      const float4* rowp = (const float4*)(gen + (size_t)j * DD);
      float4 a0 = rowp[gl * 2], a1 = rowp[gl * 2 + 1];
      float acc = a0.x * b0.x + a0.y * b0.y + a0.z * b0.z + a0.w * b0.w +
                  a1.x * b1.x + a1.y * b1.y + a1.z * b1.z + a1.w * b1.w;
      acc += __shfl_xor(acc, 1);
      acc += __shfl_xor(acc, 2);
      acc += __shfl_xor(acc, 4);
      acc += __shfl_xor(acc, 8);
      if (gl == 0) logits[j] = acc;
    }
    __syncthreads();
    float lv[4];
    float m = -INFINITY;
#pragma unroll
    for (int k = 0; k < 4; ++k) {
      lv[k] = logits[tid + 256 * k];
      m = fmaxf(m, lv[k]);
      out_logits[(size_t)i * BB + tid + 256 * k] = lv[k];
    }
    m = waveReduceMax(m);
    if (lane == 0) red[w] = m;
    __syncthreads();
    float M = fmaxf(fmaxf(red[0], red[1]), fmaxf(red[2], red[3]));
    float s = 0.f;
#pragma unroll
    for (int k = 0; k < 4; ++k) s += expf(lv[k] - M);
    s = waveReduceSum(s);
    if (lane == 0) red[4 + w] = s;
    __syncthreads();
    float S = red[4] + red[5] + red[6] + red[7];
    float lse = M + logf(S);
    float gmx_i = gm_max[i];
    float inv_i = 1.0f / gm_den[i];
    float c = 0.f;
#pragma unroll
    for (int k = 0; k < 4; ++k) {
      int j = tid + 256 * k;
      float lp = lv[k] - lse;
      float wij = expf(gm[(size_t)i * BB + j] - gmx_i) * inv_i;
      float wji = expf(gm[(size_t)j * BB + i] - gm_max[j]) / gm_den[j];
      c += (wij + wji) * lp;
    }
    c = waveReduceSum(c);
    __syncthreads();
    if (lane == 0) red[w] = c;
    __syncthreads();
    if (tid == 0) graph_partial[i] = red[0] + red[1] + red[2] + red[3];
  }
}

// K3: deterministic final reduce of the 1024-element partial arrays.
__global__ __launch_bounds__(256) void final_kernel(
    const float* __restrict__ node_partial,
    const float* __restrict__ graph_partial, float* __restrict__ out) {
  int tid = threadIdx.x;
  int lane = tid & 63, wid = tid >> 6;
  __shared__ float red[8];
  float ns = 0.f, gs = 0.f;
#pragma unroll
  for (int k = 0; k < 4; ++k) {
    ns += node_partial[tid + 256 * k];
    gs += graph_partial[tid + 256 * k];
  }
  ns = waveReduceSum(ns);
  gs = waveReduceSum(gs);
  if (lane == 0) { red[wid] = ns; red[4 + wid] = gs; }
  __syncthreads();
  if (tid == 0) {
    float nsum = red[0] + red[1] + red[2] + red[3];
    float gsum = red[4] + red[5] + red[6] + red[7];
    float node_loss = -nsum / (float)NN;
    float graph_loss = -gsum / (float)BB;
    float loss = 0.5f * node_loss + 0.5f * graph_loss;
    out[0] = loss;
    out[1] = node_loss;
    out[2] = graph_loss;
  }
}

extern "C" void kernel_launch(void* const* d_in, const int* in_sizes, int n_in,
                              void* d_out, int out_size, void* d_ws,
                              size_t ws_size, hipStream_t stream) {
  const float* ne = (const float*)d_in[0];   // [1024,128]
  const float* ge = (const float*)d_in[1];   // [1024,128]
  const float* gm = (const float*)d_in[2];   // [1024,1024]
  float* out = (float*)d_out;
  float* ws = (float*)d_ws;

  float* ne_n = ws;                    // 131072
  float* ge_n = ws + 131072;           // 131072
  float* gm_max = ws + 262144;         // 1024
  float* gm_den = ws + 263168;         // 1024
  float* node_partial = ws + 264192;   // 1024
  float* graph_partial = ws + 265216;  // 1024

  float* out_logits = out + 3;                       // [1024,1024]
  float* out_pair = out + 3 + (size_t)NN * NN;       // [1024*1024, 256]

  hipLaunchKernelGGL(prep_kernel, dim3((NN + 2 * BB) / 4), dim3(256), 0,
                     stream, ne, ge, gm, ne_n, ge_n, gm_max, gm_den);
  hipLaunchKernelGGL(fused_kernel, dim3(10240), dim3(256), 0, stream,
                     ne_n, ge_n, gm, gm_max, gm_den, out_logits,
                     out_pair, node_partial, graph_partial);
  hipLaunchKernelGGL(final_kernel, dim3(1), dim3(256), 0, stream,
                     node_partial, graph_partial, out);
}